// Round 1
// 64.300 us; speedup vs baseline: 1.0835x; 1.0835x over previous
//
#include <hip/hip_runtime.h>
#include <math.h>

#define NN 256
#define DD 256
#define KK 16
#define M_MARGIN 0.6f
#define T_THRESH 0.0025f
#define EPS 1e-12f

// Block i handles row i with 1024 threads: 4 lanes (s = t&3) share candidate
// j = t>>2, splitting the D-loop four ways (interleaved float4 quarters) and
// the rank scan; partials combine via two __shfl_xor steps. Row j is
// register-prefetched (16 x float4) BEFORE the row-i norm phase so L2 latency
// overlaps the shuffle/barrier work. Gram identity
// ||a_i - a_j||^2 = 2 - 2*(y_i.y_j)/(n_i*n_j) avoids materializing the
// normalized matrices. Per-block partial goes to ws[i]; a tiny second kernel
// reduces — no memset, no same-address atomics.
__global__ void __launch_bounds__(1024) blcd_row_kernel(
    const float* __restrict__ yi, const float* __restrict__ yit,
    float* __restrict__ partial)
{
    __shared__ float s_yi[DD];    // raw row i
    __shared__ float s_yit[DD];   // raw row i (tilde)
    __shared__ float sdis[NN];    // dis_yii[i][:]
    __shared__ float red[48];     // 16 wave partials x 3 reduced quantities

    const int i = blockIdx.x;
    const int t = threadIdx.x;    // 0..1023
    const int j = t >> 2;         // candidate row 0..255
    const int s = t & 3;          // quarter of the D-range
    const int w = t >> 6;         // wave id 0..15

    // Issue row-i staging loads first (they retire first in vmcnt order).
    float a = 0.0f, b = 0.0f;
    if (t < DD) {
        a = yi [i * DD + t];
        b = yit[i * DD + t];
    }

    // Prefetch this lane's quarter of row j: d4 = 4k + s. Lanes 4g..4g+3 read
    // 4 adjacent float4 (64B contiguous per row per step) — fully coalesced.
    const float4* __restrict__ rj = (const float4*)(yi + j * DD);
    float4 p[16];
    #pragma unroll
    for (int k = 0; k < 16; ++k) p[k] = rj[4 * k + s];

    if (t < DD) { s_yi[t] = a; s_yit[t] = b; }

    // Row-i norms / cross (waves 4..15 contribute exact zeros).
    float r0 = a * a, r1 = b * b, r2 = a * b;
    #pragma unroll
    for (int off = 32; off > 0; off >>= 1) {
        r0 += __shfl_down(r0, off, 64);
        r1 += __shfl_down(r1, off, 64);
        r2 += __shfl_down(r2, off, 64);
    }
    if ((t & 63) == 0) { red[w] = r0; red[16 + w] = r1; red[32 + w] = r2; }
    __syncthreads();

    // Only waves 0..3 held data (t < 256); their 4 partials are the sums.
    const float nn_i  = (red[0]  + red[1])  + (red[2]  + red[3]);
    const float nn_it = (red[16] + red[17]) + (red[18] + red[19]);
    const float cross = (red[32] + red[33]) + (red[34] + red[35]);
    const float inv_ni  = 1.0f / sqrtf(nn_i  + EPS);
    const float inv_nit = 1.0f / sqrtf(nn_it + EPS);

    // Quarter D-loop out of registers + LDS broadcast.
    const float4* __restrict__ si  = (const float4*)s_yi;
    const float4* __restrict__ sit = (const float4*)s_yit;
    float4 q4  = make_float4(0.f, 0.f, 0.f, 0.f);
    float4 qt4 = make_float4(0.f, 0.f, 0.f, 0.f);
    float4 nn4 = make_float4(0.f, 0.f, 0.f, 0.f);
    #pragma unroll
    for (int k = 0; k < 16; ++k) {
        const int d4 = 4 * k + s;
        float4 y = p[k];
        float4 u = si[d4];
        float4 v = sit[d4];
        q4.x  += y.x * u.x; q4.y  += y.y * u.y; q4.z  += y.z * u.z; q4.w  += y.w * u.w;
        qt4.x += y.x * v.x; qt4.y += y.y * v.y; qt4.z += y.z * v.z; qt4.w += y.w * v.w;
        nn4.x += y.x * y.x; nn4.y += y.y * y.y; nn4.z += y.z * y.z; nn4.w += y.w * y.w;
    }
    float q  = (q4.x  + q4.y ) + (q4.z  + q4.w );
    float qt = (qt4.x + qt4.y) + (qt4.z + qt4.w);
    float nn = (nn4.x + nn4.y) + (nn4.z + nn4.w);
    // Combine the four quarters (lanes s, s^1, s^2 are in the same wave).
    q  += __shfl_xor(q,  1, 64);  q  += __shfl_xor(q,  2, 64);
    qt += __shfl_xor(qt, 1, 64);  qt += __shfl_xor(qt, 2, 64);
    nn += __shfl_xor(nn, 1, 64);  nn += __shfl_xor(nn, 2, 64);

    const float inv_nt = 1.0f / sqrtf(nn + EPS);
    const float c    = q  * inv_nt * inv_ni;
    const float ct   = qt * inv_nt * inv_nit;
    const float myv  = 0.5f * sqrtf(fmaxf(2.0f - 2.0f * c , 0.0f) + EPS);
    const float myvt = 0.5f * sqrtf(fmaxf(2.0f - 2.0f * ct, 0.0f) + EPS);
    if (s == 0) sdis[j] = myv;
    __syncthreads();

    // Stable rank == top_k position (ties -> lower index first), 4-way split.
    // k = 4m + s keeps the four lanes' reads 16B apart -> conflict-free.
    int rank = 0;
    const float4* sd4 = (const float4*)sdis;
    #pragma unroll
    for (int m = 0; m < 16; ++m) {
        const int k = 4 * m + s;
        float4 v = sd4[k];
        const int jj = k * 4;
        rank += (v.x < myv || (v.x == myv && (jj + 0) < j)) ? 1 : 0;
        rank += (v.y < myv || (v.y == myv && (jj + 1) < j)) ? 1 : 0;
        rank += (v.z < myv || (v.z == myv && (jj + 2) < j)) ? 1 : 0;
        rank += (v.w < myv || (v.w == myv && (jj + 3) < j)) ? 1 : 0;
    }
    rank += __shfl_xor(rank, 1, 64);
    rank += __shfl_xor(rank, 2, 64);

    float contrib = 0.0f;
    if (s == 0) {
        if (rank >= 1 && rank <= KK) {      // e1 term: j is one of the 16 nbrs
            const float dd = myv - myvt;
            contrib = dd * dd - T_THRESH;
        }
        if (rank == 1) {                    // e2 hinge: j is the 2nd-NN
            const float cc = cross * inv_ni * inv_nit;
            const float d_iit = 0.5f * sqrtf(fmaxf(2.0f - 2.0f * cc, 0.0f) + EPS);
            contrib += fmaxf(d_iit + M_MARGIN - myv, 0.0f);
        }
    }

    // Block reduce (16 waves) -> one plain store per block (no atomics).
    #pragma unroll
    for (int off = 32; off > 0; off >>= 1) contrib += __shfl_down(contrib, off, 64);
    // All reads of red[] happened before the sdis __syncthreads above -> safe.
    if ((t & 63) == 0) red[w] = contrib;
    __syncthreads();
    if (t == 0) {
        float tot = ((red[0]  + red[1])  + (red[2]  + red[3]))
                  + ((red[4]  + red[5])  + (red[6]  + red[7]))
                  + ((red[8]  + red[9])  + (red[10] + red[11]))
                  + ((red[12] + red[13]) + (red[14] + red[15]));
        partial[i] = tot;
    }
}

// 256 partials -> scalar. Plain store; output needs no pre-zeroing.
__global__ void __launch_bounds__(NN) blcd_reduce_kernel(
    const float* __restrict__ partial, float* __restrict__ out)
{
    __shared__ float red[4];
    const int t = threadIdx.x;
    float v = partial[t];
    #pragma unroll
    for (int off = 32; off > 0; off >>= 1) v += __shfl_down(v, off, 64);
    if ((t & 63) == 0) red[t >> 6] = v;
    __syncthreads();
    if (t == 0) out[0] = (red[0] + red[1]) + (red[2] + red[3]);
}

extern "C" void kernel_launch(void* const* d_in, const int* in_sizes, int n_in,
                              void* d_out, int out_size, void* d_ws, size_t ws_size,
                              hipStream_t stream) {
    (void)in_sizes; (void)n_in; (void)out_size; (void)ws_size;

    const float* yi  = (const float*)d_in[0];
    const float* yit = (const float*)d_in[1];
    float* out = (float*)d_out;
    float* ws  = (float*)d_ws;

    blcd_row_kernel<<<NN, 1024, 0, stream>>>(yi, yit, ws);
    blcd_reduce_kernel<<<1, NN, 0, stream>>>(ws, out);
}